// Round 7
// baseline (88.869 us; speedup 1.0000x reference)
//
#include <hip/hip_runtime.h>
#include <math.h>

#define K_ 32
#define D_ 8
#define CSTRIDE 48   // 36 tri + 8 zm + 1 cst + 3 pad per component (192 B)
#define S_ 4         // samples per thread: amortizes the 12 ds_read_b128/k
                     // over 4 samples -> LDS pipe (1152 cyc/CU/k) ~ VALU
                     // (944 cyc/CU/k); S=1 was LDS-bound at 58 us (round 2).

// ---------------------------------------------------------------------------
// Single fused kernel (round-5 evidence: s_load main ran ~2.3x the VALU floor
// and was occupancy-insensitive; round-2 evidence validates the ds_read_b128
// broadcast cost model at 12 cyc/read).
//
// Phase 1 (lanes 0..31 of wave 0, per block, redundantly): per-component
// constants into LDS. cov = tril(L)tril(L)^T + eps*I => chol(cov) = L*sign;
// maha/logdet are sign-invariant and eps is O(1e-6) rel, so invert tril(L)
// directly (no Cholesky). Log2 domain: scale by sqrt(log2e/2) so the online
// LSE uses v_exp_f32 (= exp2) natively.
//   Ci'  = L^{-1} * sqrt(log2e/2)
//   zm'  = (L^{-1} mean) * sqrt(log2e/2)
//   cst2 = [log_softmax(pi)_k - 0.5*(2 sum log|L_ii| + D log 2pi)] * log2e
//   W_k(x) = cst2_k - sum_i ((Ci' x)_i - zm'_i)^2     (in log2 units)
//   out = ln2 * log2sumexp2_k W_k
// Phase 2: S_=4 samples/thread, k-loop rolled, constants re-read per k as 12
// broadcast ds_read_b128 (conflict-free), online branch-free logsumexp.
// ---------------------------------------------------------------------------
__global__ __launch_bounds__(256) void gmm_fused(
    const float* __restrict__ x,
    const float* __restrict__ pi,
    const float* __restrict__ means,
    const float* __restrict__ chol,
    float* __restrict__ out, int N)
{
    __shared__ float cv[K_ * CSTRIDE];

    const int tid = threadIdx.x;
    if (tid < K_) {
        const int k = tid;

        float L[D_][D_];
#pragma unroll
        for (int i = 0; i < D_; ++i)
#pragma unroll
            for (int j = 0; j <= i; ++j)
                L[i][j] = chol[k * D_ * D_ + i * D_ + j];

        float rd[D_];
#pragma unroll
        for (int i = 0; i < D_; ++i) rd[i] = 1.f / L[i][i];

        // forward-substitution inverse of tril(L)
        float Ci[D_][D_];
#pragma unroll
        for (int j = 0; j < D_; ++j) {
            Ci[j][j] = rd[j];
#pragma unroll
            for (int i = j + 1; i < D_; ++i) {
                float s = 0.f;
#pragma unroll
                for (int m = j; m < i; ++m) s += L[i][m] * Ci[m][j];
                Ci[i][j] = -s * rd[i];
            }
        }

        float logdet = 0.f;
#pragma unroll
        for (int i = 0; i < D_; ++i) logdet += __logf(fabsf(L[i][i]));
        logdet *= 2.f;

        float zm[D_];
#pragma unroll
        for (int i = 0; i < D_; ++i) {
            float s = 0.f;
#pragma unroll
            for (int j = 0; j <= i; ++j) s += Ci[i][j] * means[k * D_ + j];
            zm[i] = s;
        }

        float mx = pi[0];
#pragma unroll
        for (int t = 1; t < K_; ++t) mx = fmaxf(mx, pi[t]);
        float se = 0.f;
#pragma unroll
        for (int t = 0; t < K_; ++t) se += __expf(pi[t] - mx);
        float lse = mx + __logf(se);

        const float LOG2PI = 1.8378770664093453f;
        const float LOG2E  = 1.4426950408889634f;
        const float SQH2   = 0.84932180028801905f;  // sqrt(0.5 * log2e)
        float cst2 = ((pi[k] - lse) - 0.5f * (logdet + (float)D_ * LOG2PI)) * LOG2E;

        float* p = cv + k * CSTRIDE;
        int t = 0;
#pragma unroll
        for (int i = 0; i < D_; ++i)
#pragma unroll
            for (int j = 0; j <= i; ++j) p[t++] = Ci[i][j] * SQH2;
#pragma unroll
        for (int i = 0; i < D_; ++i) p[36 + i] = zm[i] * SQH2;
        p[44] = cst2;
        p[45] = 0.f; p[46] = 0.f; p[47] = 0.f;
    }
    __syncthreads();

    const int q = N >> 2;  // N / S_
    const int t = blockIdx.x * 256 + tid;
    if (t >= q) return;

    float xv[S_][D_];
#pragma unroll
    for (int s = 0; s < S_; ++s) {
        const float4* xp = (const float4*)x + (size_t)(t + s * q) * 2;
        float4 a = xp[0], b = xp[1];
        xv[s][0] = a.x; xv[s][1] = a.y; xv[s][2] = a.z; xv[s][3] = a.w;
        xv[s][4] = b.x; xv[s][5] = b.y; xv[s][6] = b.z; xv[s][7] = b.w;
    }

    float m[S_], sm[S_];
#pragma unroll
    for (int s = 0; s < S_; ++s) { m[s] = -INFINITY; sm[s] = 0.f; }

#pragma unroll 1
    for (int k = 0; k < K_; ++k) {
        // 12 broadcast ds_read_b128 (wave-uniform address, conflict-free)
        float c[CSTRIDE];
        {
            const float4* ps = (const float4*)(cv + k * CSTRIDE);
            float4* cd = (float4*)c;
#pragma unroll
            for (int qq = 0; qq < 12; ++qq) cd[qq] = ps[qq];
        }

        float w[S_];
#pragma unroll
        for (int s = 0; s < S_; ++s) w[s] = c[44];
        int tt = 0;
#pragma unroll
        for (int i = 0; i < D_; ++i) {
            float z[S_];
#pragma unroll
            for (int s = 0; s < S_; ++s) z[s] = -c[36 + i];
#pragma unroll
            for (int j = 0; j <= i; ++j)
#pragma unroll
                for (int s = 0; s < S_; ++s)
                    z[s] = fmaf(c[tt + j], xv[s][j], z[s]);
            tt += i + 1;
#pragma unroll
            for (int s = 0; s < S_; ++s) w[s] = fmaf(-z[s], z[s], w[s]);
        }

        // online log2-sum-exp2, branch-free, 1 v_exp_f32 per (sample,k)
#pragma unroll
        for (int s = 0; s < S_; ++s) {
            float d = w[s] - m[s];
            float e = exp2f(-fabsf(d));   // device exp2f -> single v_exp_f32
            sm[s] = (d > 0.f) ? fmaf(sm[s], e, 1.f) : (sm[s] + e);
            m[s] = fmaxf(m[s], w[s]);
        }
    }

    const float LN2 = 0.69314718055994531f;
#pragma unroll
    for (int s = 0; s < S_; ++s)
        out[t + s * q] = (m[s] + log2f(sm[s])) * LN2;
}

extern "C" void kernel_launch(void* const* d_in, const int* in_sizes, int n_in,
                              void* d_out, int out_size, void* d_ws, size_t ws_size,
                              hipStream_t stream) {
    const float* x     = (const float*)d_in[0];
    const float* pi    = (const float*)d_in[1];
    const float* means = (const float*)d_in[2];
    const float* chol  = (const float*)d_in[3];
    float* out = (float*)d_out;

    int N = in_sizes[0] / D_;
    int q = N >> 2;  // threads = N / S_

    gmm_fused<<<(q + 255) / 256, 256, 0, stream>>>(x, pi, means, chol, out, N);
}